// Round 1
// baseline (1332.092 us; speedup 1.0000x reference)
//
#include <hip/hip_runtime.h>
#include <hip/hip_bf16.h>
#include <math.h>

// Problem constants (from reference setup_inputs)
#define BZ   8      // batch
#define DD   512    // z feature dim = H*dh
#define LL   2048   // sequence
#define HH   8      // heads
#define MM   1024   // codes per head
#define DH   64     // code dim
#define NN   (BZ * LL)          // 16384 rows per head
#define TOTAL_ELEMS (HH * NN * DH)   // 8388608, for the mean

// d_out layout (floats): [z_q (8388608)] [vq_loss (1)] [indices (131072)] [codebooks (524288)]
#define OFF_ZQ   0
#define OFF_LOSS 8388608
#define OFF_IDX  8388609
#define OFF_CB   8519681

// d_ws layout (floats): [sums (HH*MM*DH = 524288)] [counts (HH*MM = 8192)] [sse (1)]
#define WS_SUMS   0
#define WS_COUNTS 524288
#define WS_SSE    532480
#define WS_FLOATS 532481

__global__ __launch_bounds__(256) void vq_assign_kernel(
    const float* __restrict__ z,          // [B, D, L]
    const float* __restrict__ cb,         // [H, M, DH]
    float* __restrict__ zq_out,           // [B, D, L]
    float* __restrict__ idx_out,          // [B, H, L] as float
    float* __restrict__ sums,             // [H, M, DH]
    float* __restrict__ counts,           // [H, M]
    float* __restrict__ sse)              // [1]
{
    const int n = blockIdx.x * 256 + threadIdx.x;   // n in [0, NN)
    const int h = blockIdx.y;
    const int b = n >> 11;          // n / LL
    const int l = n & (LL - 1);     // n % LL

    // Load this row's z vector into registers. z_split[h,n,k] = z[b, h*64+k, l]
    const float* __restrict__ zp = z + ((size_t)(b * DD + h * DH) * LL + l);
    float zr[DH];
#pragma unroll
    for (int k = 0; k < DH; ++k) zr[k] = zp[(size_t)k * LL];

    const float* __restrict__ cbh = cb + (size_t)h * MM * DH;

    // fp32 scan for top-2 (4 independent accumulator chains for ILP).
    float b1 = -1e30f, b2 = -1e30f;
    int i1 = 0, i2 = 0;
    for (int m = 0; m < MM; ++m) {
        const float* __restrict__ c = cbh + m * DH;   // wave-uniform address -> s_load
        float a0 = 0.f, a1 = 0.f, a2 = 0.f, a3 = 0.f;
#pragma unroll
        for (int k = 0; k < DH; k += 4) {
            a0 = fmaf(zr[k + 0], c[k + 0], a0);
            a1 = fmaf(zr[k + 1], c[k + 1], a1);
            a2 = fmaf(zr[k + 2], c[k + 2], a2);
            a3 = fmaf(zr[k + 3], c[k + 3], a3);
        }
        const float s = (a0 + a1) + (a2 + a3);
        if (s > b1) { b2 = b1; i2 = i1; b1 = s; i1 = m; }
        else if (s > b2) { b2 = s; i2 = m; }
    }

    // fp64 refinement of the two candidates (resolves fp32 near-ties exactly).
    const float* __restrict__ c1 = cbh + i1 * DH;
    const float* __restrict__ c2 = cbh + i2 * DH;
    double d1 = 0.0, d2 = 0.0;
#pragma unroll
    for (int k = 0; k < DH; ++k) {
        d1 = fma((double)zr[k], (double)c1[k], d1);
        d2 = fma((double)zr[k], (double)c2[k], d2);
    }
    // argmax takes first occurrence on exact tie
    const int best = (d2 > d1 || (d2 == d1 && i2 < i1)) ? i2 : i1;

    // Outputs: quantized vector, squared error, segment sums.
    const float* __restrict__ cq = cbh + best * DH;
    float* __restrict__ zqp = zq_out + ((size_t)(b * DD + h * DH) * LL + l);
    float* __restrict__ srow = sums + ((size_t)h * MM + best) * DH;
    float err = 0.f;
#pragma unroll
    for (int k = 0; k < DH; ++k) {
        const float q = cq[k];
        zqp[(size_t)k * LL] = q;
        const float dk = zr[k] - q;
        err = fmaf(dk, dk, err);
        atomicAdd(&srow[k], zr[k]);
    }
    atomicAdd(&counts[h * MM + best], 1.0f);
    idx_out[((size_t)b * HH + h) * LL + l] = (float)best;

    // wave-level reduce of err, then one atomic per wave
#pragma unroll
    for (int off = 32; off; off >>= 1) err += __shfl_xor(err, off, 64);
    if ((threadIdx.x & 63) == 0) atomicAdd(sse, err);
}

__global__ __launch_bounds__(256) void vq_update_kernel(
    const float* __restrict__ cb,       // [H, M, DH]
    const float* __restrict__ sums,
    const float* __restrict__ counts,
    const float* __restrict__ sse,
    float* __restrict__ cb_out,         // [H, M, DH]
    float* __restrict__ loss_out)       // [1]
{
    if (blockIdx.x == 0 && threadIdx.x == 0) {
        loss_out[0] = 1.25f * sse[0] / (float)TOTAL_ELEMS;
    }
    const int row  = blockIdx.x * 4 + (threadIdx.x >> 6);   // (h*MM + m), one wave per row
    const int lane = threadIdx.x & 63;

    const float cnt  = counts[row];
    const float c    = cb[(size_t)row * DH + lane];
    const float mean = sums[(size_t)row * DH + lane] / fmaxf(cnt, 1.0f);

    float dot = mean * c;
    float nl  = mean * mean;
    float nh  = c * c;
#pragma unroll
    for (int off = 32; off; off >>= 1) {
        dot += __shfl_xor(dot, off, 64);
        nl  += __shfl_xor(nl,  off, 64);
        nh  += __shfl_xor(nh,  off, 64);
    }

    float cosv = dot / fmaxf(sqrtf(nl) * sqrtf(nh), 1e-8f);
    cosv = fminf(fmaxf(cosv, -0.9999999f), 0.9999999f);
    const float omega = acosf(cosv);
    const float so    = sinf(omega);
    // slerp(means, cb, val=0.99): (means*sin((1-val)*omega) + cb*sin(val*omega)) / so
    float outv = (mean * sinf(0.01f * omega) + c * sinf(0.99f * omega)) / so;

    // rms_norm over the row
    float ms = outv * outv;
#pragma unroll
    for (int off = 32; off; off >>= 1) ms += __shfl_xor(ms, off, 64);
    ms = ms * (1.0f / (float)DH) + 1.1920929e-07f;
    const float normed = outv / sqrtf(ms);

    cb_out[(size_t)row * DH + lane] = (cnt > 0.f) ? normed : c;
}

extern "C" void kernel_launch(void* const* d_in, const int* in_sizes, int n_in,
                              void* d_out, int out_size, void* d_ws, size_t ws_size,
                              hipStream_t stream) {
    const float* z  = (const float*)d_in[0];
    const float* cb = (const float*)d_in[1];
    float* out = (float*)d_out;
    float* ws  = (float*)d_ws;

    // zero the accumulator workspace (sums, counts, sse)
    hipMemsetAsync(d_ws, 0, (size_t)WS_FLOATS * sizeof(float), stream);

    dim3 gridA(NN / 256, HH);
    vq_assign_kernel<<<gridA, 256, 0, stream>>>(
        z, cb,
        out + OFF_ZQ, out + OFF_IDX,
        ws + WS_SUMS, ws + WS_COUNTS, ws + WS_SSE);

    dim3 gridB((HH * MM) / 4);
    vq_update_kernel<<<gridB, 256, 0, stream>>>(
        cb, ws + WS_SUMS, ws + WS_COUNTS, ws + WS_SSE,
        out + OFF_CB, out + OFF_LOSS);
}

// Round 2
// 1324.702 us; speedup vs baseline: 1.0056x; 1.0056x over previous
//
#include <hip/hip_runtime.h>
#include <hip/hip_bf16.h>
#include <math.h>

// Problem constants (from reference setup_inputs)
#define BZ   8      // batch
#define DD   512    // z feature dim = H*dh
#define LL   2048   // sequence
#define HH   8      // heads
#define MM   1024   // codes per head
#define DH   64     // code dim
#define NN   (BZ * LL)          // 16384 rows per head
#define TOTAL_ELEMS (HH * NN * DH)   // 8388608, for the mean

// d_out layout (floats): [z_q (8388608)] [vq_loss (1)] [indices (131072)] [codebooks (524288)]
#define OFF_ZQ   0
#define OFF_LOSS 8388608
#define OFF_IDX  8388609
#define OFF_CB   8519681

// d_ws layout (floats): [sums (HH*MM*DH = 524288)] [counts (HH*MM = 8192)] [sse (1)]
#define WS_SUMS   0
#define WS_COUNTS 524288
#define WS_SSE    532480
#define WS_FLOATS 532481

// __launch_bounds__(256, 3): min 3 waves/EU -> VGPR cap ~170. We need ~100
// (zr[64] resident + accumulators + addresses). Round-1 default occupancy
// targeting gave VGPR_Count=52 => compiler rematerialized the z-row loads
// inside the m-loop => 11% VALUBusy, latency-bound.
__global__ __launch_bounds__(256, 3) void vq_assign_kernel(
    const float* __restrict__ z,          // [B, D, L]
    const float* __restrict__ cb,         // [H, M, DH]
    float* __restrict__ zq_out,           // [B, D, L]
    float* __restrict__ idx_out,          // [B, H, L] as float
    float* __restrict__ sums,             // [H, M, DH]
    float* __restrict__ counts,           // [H, M]
    float* __restrict__ sse)              // [1]
{
    const int n = blockIdx.x * 256 + threadIdx.x;   // n in [0, NN)
    const int h = blockIdx.y;
    const int b = n >> 11;          // n / LL
    const int l = n & (LL - 1);     // n % LL

    // Load this row's z vector into registers. z_split[h,n,k] = z[b, h*64+k, l]
    const float* __restrict__ zp = z + ((size_t)(b * DD + h * DH) * LL + l);
    float zr[DH];
#pragma unroll
    for (int k = 0; k < DH; ++k) zr[k] = zp[(size_t)k * LL];

    const float* __restrict__ cbh = cb + (size_t)h * MM * DH;

    // fp32 scan for top-2 (4 independent accumulator chains for ILP).
    // m-loop NOT unrolled: one codebook row = 64 SGPRs; unroll-by-2 would
    // exceed the 102-SGPR file and force de-scalarization.
    float b1 = -1e30f, b2 = -1e30f;
    int i1 = 0, i2 = 0;
#pragma unroll 1
    for (int m = 0; m < MM; ++m) {
        const float* __restrict__ c = cbh + m * DH;   // wave-uniform address -> s_load
        float a0 = 0.f, a1 = 0.f, a2 = 0.f, a3 = 0.f;
#pragma unroll
        for (int k = 0; k < DH; k += 4) {
            a0 = fmaf(zr[k + 0], c[k + 0], a0);
            a1 = fmaf(zr[k + 1], c[k + 1], a1);
            a2 = fmaf(zr[k + 2], c[k + 2], a2);
            a3 = fmaf(zr[k + 3], c[k + 3], a3);
        }
        const float s = (a0 + a1) + (a2 + a3);
        if (s > b1) { b2 = b1; i2 = i1; b1 = s; i1 = m; }
        else if (s > b2) { b2 = s; i2 = m; }
    }

    // fp64 refinement of the two candidates (resolves fp32 near-ties exactly).
    const float* __restrict__ c1 = cbh + i1 * DH;
    const float* __restrict__ c2 = cbh + i2 * DH;
    double d1 = 0.0, d2 = 0.0;
#pragma unroll
    for (int k = 0; k < DH; ++k) {
        d1 = fma((double)zr[k], (double)c1[k], d1);
        d2 = fma((double)zr[k], (double)c2[k], d2);
    }
    // argmax takes first occurrence on exact tie
    const int best = (d2 > d1 || (d2 == d1 && i2 < i1)) ? i2 : i1;

    // Outputs: quantized vector, squared error, segment sums.
    const float* __restrict__ cq = cbh + best * DH;
    float* __restrict__ zqp = zq_out + ((size_t)(b * DD + h * DH) * LL + l);
    float* __restrict__ srow = sums + ((size_t)h * MM + best) * DH;
    float err = 0.f;
#pragma unroll
    for (int k = 0; k < DH; ++k) {
        const float q = cq[k];
        zqp[(size_t)k * LL] = q;
        const float dk = zr[k] - q;
        err = fmaf(dk, dk, err);
        atomicAdd(&srow[k], zr[k]);
    }
    atomicAdd(&counts[h * MM + best], 1.0f);
    idx_out[((size_t)b * HH + h) * LL + l] = (float)best;

    // wave-level reduce of err, then one atomic per wave
#pragma unroll
    for (int off = 32; off; off >>= 1) err += __shfl_xor(err, off, 64);
    if ((threadIdx.x & 63) == 0) atomicAdd(sse, err);
}

__global__ __launch_bounds__(256) void vq_update_kernel(
    const float* __restrict__ cb,       // [H, M, DH]
    const float* __restrict__ sums,
    const float* __restrict__ counts,
    const float* __restrict__ sse,
    float* __restrict__ cb_out,         // [H, M, DH]
    float* __restrict__ loss_out)       // [1]
{
    if (blockIdx.x == 0 && threadIdx.x == 0) {
        loss_out[0] = 1.25f * sse[0] / (float)TOTAL_ELEMS;
    }
    const int row  = blockIdx.x * 4 + (threadIdx.x >> 6);   // (h*MM + m), one wave per row
    const int lane = threadIdx.x & 63;

    const float cnt  = counts[row];
    const float c    = cb[(size_t)row * DH + lane];
    const float mean = sums[(size_t)row * DH + lane] / fmaxf(cnt, 1.0f);

    float dot = mean * c;
    float nl  = mean * mean;
    float nh  = c * c;
#pragma unroll
    for (int off = 32; off; off >>= 1) {
        dot += __shfl_xor(dot, off, 64);
        nl  += __shfl_xor(nl,  off, 64);
        nh  += __shfl_xor(nh,  off, 64);
    }

    float cosv = dot / fmaxf(sqrtf(nl) * sqrtf(nh), 1e-8f);
    cosv = fminf(fmaxf(cosv, -0.9999999f), 0.9999999f);
    const float omega = acosf(cosv);
    const float so    = sinf(omega);
    // slerp(means, cb, val=0.99): (means*sin((1-val)*omega) + cb*sin(val*omega)) / so
    float outv = (mean * sinf(0.01f * omega) + c * sinf(0.99f * omega)) / so;

    // rms_norm over the row
    float ms = outv * outv;
#pragma unroll
    for (int off = 32; off; off >>= 1) ms += __shfl_xor(ms, off, 64);
    ms = ms * (1.0f / (float)DH) + 1.1920929e-07f;
    const float normed = outv / sqrtf(ms);

    cb_out[(size_t)row * DH + lane] = (cnt > 0.f) ? normed : c;
}

extern "C" void kernel_launch(void* const* d_in, const int* in_sizes, int n_in,
                              void* d_out, int out_size, void* d_ws, size_t ws_size,
                              hipStream_t stream) {
    const float* z  = (const float*)d_in[0];
    const float* cb = (const float*)d_in[1];
    float* out = (float*)d_out;
    float* ws  = (float*)d_ws;

    // zero the accumulator workspace (sums, counts, sse)
    hipMemsetAsync(d_ws, 0, (size_t)WS_FLOATS * sizeof(float), stream);

    dim3 gridA(NN / 256, HH);
    vq_assign_kernel<<<gridA, 256, 0, stream>>>(
        z, cb,
        out + OFF_ZQ, out + OFF_IDX,
        ws + WS_SUMS, ws + WS_COUNTS, ws + WS_SSE);

    dim3 gridB((HH * MM) / 4);
    vq_update_kernel<<<gridB, 256, 0, stream>>>(
        cb, ws + WS_SUMS, ws + WS_COUNTS, ws + WS_SSE,
        out + OFF_CB, out + OFF_LOSS);
}

// Round 3
// 947.386 us; speedup vs baseline: 1.4061x; 1.3983x over previous
//
#include <hip/hip_runtime.h>
#include <hip/hip_bf16.h>
#include <math.h>

// Problem constants (from reference setup_inputs)
#define BZ   8      // batch
#define DD   512    // z feature dim = H*dh
#define LL   2048   // sequence
#define HH   8      // heads
#define MM   1024   // codes per head
#define DH   64     // code dim
#define NN   (BZ * LL)          // 16384 rows per head
#define TOTAL_ELEMS (HH * NN * DH)   // 8388608, for the mean

// d_out layout (floats): [z_q (8388608)] [vq_loss (1)] [indices (131072)] [codebooks (524288)]
#define OFF_ZQ   0
#define OFF_LOSS 8388608
#define OFF_IDX  8388609
#define OFF_CB   8519681

// d_ws layout (floats): [sums (HH*MM*DH = 524288)] [counts (HH*MM = 8192)] [sse (1)]
#define WS_SUMS   0
#define WS_COUNTS 524288
#define WS_SSE    532480
#define WS_FLOATS 532481

// R1/R2 lesson: launch_bounds(256,3) did NOT stop the scheduler from
// sinking the loop-invariant zr loads into the m-loop (VGPR stayed 52,
// VALUBusy 11%). The empty asm ties below make each zr[k] the result of a
// non-rematerializable asm def, forcing all 64 values to stay resident in
// VGPRs across the scan loop.
__global__ __launch_bounds__(256, 3) void vq_assign_kernel(
    const float* __restrict__ z,          // [B, D, L]
    const float* __restrict__ cb,         // [H, M, DH]
    float* __restrict__ zq_out,           // [B, D, L]
    float* __restrict__ idx_out,          // [B, H, L] as float
    float* __restrict__ sums,             // [H, M, DH]
    float* __restrict__ counts,           // [H, M]
    float* __restrict__ sse)              // [1]
{
    const int n = blockIdx.x * 256 + threadIdx.x;   // n in [0, NN)
    const int h = blockIdx.y;
    const int b = n >> 11;          // n / LL
    const int l = n & (LL - 1);     // n % LL

    // Load this row's z vector into registers. z_split[h,n,k] = z[b, h*64+k, l]
    const float* __restrict__ zp = z + ((size_t)(b * DD + h * DH) * LL + l);
    float zr[DH];
#pragma unroll
    for (int k = 0; k < DH; ++k) zr[k] = zp[(size_t)k * LL];
    // Pin: forbid remat/sinking of the z-row loads into the scan loop.
#pragma unroll
    for (int k = 0; k < DH; ++k) asm volatile("" : "+v"(zr[k]));

    const float* __restrict__ cbh = cb + (size_t)h * MM * DH;

    // fp32 scan for top-2 (4 independent accumulator chains for ILP).
    // m-loop NOT unrolled: one codebook row = 64 SGPRs; unroll-by-2 would
    // exceed the SGPR file and force de-scalarization.
    float b1 = -1e30f, b2 = -1e30f;
    int i1 = 0, i2 = 0;
#pragma unroll 1
    for (int m = 0; m < MM; ++m) {
        const float* __restrict__ c = cbh + m * DH;   // wave-uniform address -> s_load
        float a0 = 0.f, a1 = 0.f, a2 = 0.f, a3 = 0.f;
#pragma unroll
        for (int k = 0; k < DH; k += 4) {
            a0 = fmaf(zr[k + 0], c[k + 0], a0);
            a1 = fmaf(zr[k + 1], c[k + 1], a1);
            a2 = fmaf(zr[k + 2], c[k + 2], a2);
            a3 = fmaf(zr[k + 3], c[k + 3], a3);
        }
        const float s = (a0 + a1) + (a2 + a3);
        // Branchless top-2 maintenance (v_cndmask chains, no divergence).
        const bool gt1 = s > b1;
        const bool gt2 = s > b2;
        b2 = gt1 ? b1 : (gt2 ? s : b2);
        i2 = gt1 ? i1 : (gt2 ? m : i2);
        b1 = gt1 ? s : b1;
        i1 = gt1 ? m : i1;
    }

    // fp64 refinement of the two candidates (resolves fp32 near-ties exactly).
    const float* __restrict__ c1 = cbh + i1 * DH;
    const float* __restrict__ c2 = cbh + i2 * DH;
    double d1 = 0.0, d2 = 0.0;
#pragma unroll
    for (int k = 0; k < DH; ++k) {
        d1 = fma((double)zr[k], (double)c1[k], d1);
        d2 = fma((double)zr[k], (double)c2[k], d2);
    }
    // argmax takes first occurrence on exact tie
    const int best = (d2 > d1 || (d2 == d1 && i2 < i1)) ? i2 : i1;

    // Outputs: quantized vector, squared error, segment sums.
    const float* __restrict__ cq = cbh + best * DH;
    float* __restrict__ zqp = zq_out + ((size_t)(b * DD + h * DH) * LL + l);
    float* __restrict__ srow = sums + ((size_t)h * MM + best) * DH;
    float err = 0.f;
#pragma unroll
    for (int k = 0; k < DH; ++k) {
        const float q = cq[k];
        zqp[(size_t)k * LL] = q;
        const float dk = zr[k] - q;
        err = fmaf(dk, dk, err);
        atomicAdd(&srow[k], zr[k]);
    }
    atomicAdd(&counts[h * MM + best], 1.0f);
    idx_out[((size_t)b * HH + h) * LL + l] = (float)best;

    // wave-level reduce of err, then one atomic per wave
#pragma unroll
    for (int off = 32; off; off >>= 1) err += __shfl_xor(err, off, 64);
    if ((threadIdx.x & 63) == 0) atomicAdd(sse, err);
}

__global__ __launch_bounds__(256) void vq_update_kernel(
    const float* __restrict__ cb,       // [H, M, DH]
    const float* __restrict__ sums,
    const float* __restrict__ counts,
    const float* __restrict__ sse,
    float* __restrict__ cb_out,         // [H, M, DH]
    float* __restrict__ loss_out)       // [1]
{
    if (blockIdx.x == 0 && threadIdx.x == 0) {
        loss_out[0] = 1.25f * sse[0] / (float)TOTAL_ELEMS;
    }
    const int row  = blockIdx.x * 4 + (threadIdx.x >> 6);   // (h*MM + m), one wave per row
    const int lane = threadIdx.x & 63;

    const float cnt  = counts[row];
    const float c    = cb[(size_t)row * DH + lane];
    const float mean = sums[(size_t)row * DH + lane] / fmaxf(cnt, 1.0f);

    float dot = mean * c;
    float nl  = mean * mean;
    float nh  = c * c;
#pragma unroll
    for (int off = 32; off; off >>= 1) {
        dot += __shfl_xor(dot, off, 64);
        nl  += __shfl_xor(nl,  off, 64);
        nh  += __shfl_xor(nh,  off, 64);
    }

    float cosv = dot / fmaxf(sqrtf(nl) * sqrtf(nh), 1e-8f);
    cosv = fminf(fmaxf(cosv, -0.9999999f), 0.9999999f);
    const float omega = acosf(cosv);
    const float so    = sinf(omega);
    // slerp(means, cb, val=0.99): (means*sin((1-val)*omega) + cb*sin(val*omega)) / so
    float outv = (mean * sinf(0.01f * omega) + c * sinf(0.99f * omega)) / so;

    // rms_norm over the row
    float ms = outv * outv;
#pragma unroll
    for (int off = 32; off; off >>= 1) ms += __shfl_xor(ms, off, 64);
    ms = ms * (1.0f / (float)DH) + 1.1920929e-07f;
    const float normed = outv / sqrtf(ms);

    cb_out[(size_t)row * DH + lane] = (cnt > 0.f) ? normed : c;
}

extern "C" void kernel_launch(void* const* d_in, const int* in_sizes, int n_in,
                              void* d_out, int out_size, void* d_ws, size_t ws_size,
                              hipStream_t stream) {
    const float* z  = (const float*)d_in[0];
    const float* cb = (const float*)d_in[1];
    float* out = (float*)d_out;
    float* ws  = (float*)d_ws;

    // zero the accumulator workspace (sums, counts, sse)
    hipMemsetAsync(d_ws, 0, (size_t)WS_FLOATS * sizeof(float), stream);

    dim3 gridA(NN / 256, HH);
    vq_assign_kernel<<<gridA, 256, 0, stream>>>(
        z, cb,
        out + OFF_ZQ, out + OFF_IDX,
        ws + WS_SUMS, ws + WS_COUNTS, ws + WS_SSE);

    dim3 gridB((HH * MM) / 4);
    vq_update_kernel<<<gridB, 256, 0, stream>>>(
        cb, ws + WS_SUMS, ws + WS_COUNTS, ws + WS_SSE,
        out + OFF_CB, out + OFF_LOSS);
}